// Round 3
// baseline (82.912 us; speedup 1.0000x reference)
//
#include <hip/hip_runtime.h>

// Simple_TensorProduct (e3nn uvw TP, MUL=256, l<=1, v=1) as two fused bf16 GEMMs.
//   out0[z,w]      = sum_k T0[z,k]    * B0[k,w]   (K=512)
//   out1[(z,c),w]  = sum_k T1[(z,c),k]* B1[k,w]   (K=768, M=3N)
// T = x1 with x2 folded in (built per z-tile, bf16, LDS, A-fragment order).
// B = weights, prescaled by path alphas, bf16, B-fragment order in d_ws.
//
// R3: z-tile 16->32 rows, u-chunk 128->64 (4 chunks). LDS unchanged (45 KB),
// but B-fragment reuse doubles (6 MFMA per B L2-load), B L2 traffic halves,
// 24 MFMA per kt-step per wave (vs 12). B prefetch chains out1->out0.
// acc = 32 f32x4 -> __launch_bounds__(256,2).

typedef short bf16x8 __attribute__((ext_vector_type(8)));
typedef float f32x4 __attribute__((ext_vector_type(4)));

static __device__ __forceinline__ unsigned short f2bf(float f) {
  unsigned int u = __builtin_bit_cast(unsigned int, f);
  u += 0x7FFFu + ((u >> 16) & 1u);   // RNE
  return (unsigned short)(u >> 16);
}

static __device__ __forceinline__ bf16x8 asbf(int4 v) {
  return __builtin_bit_cast(bf16x8, v);
}

// ---------------------------------------------------------------------------
// Weight prep: fp32 weights -> prescaled bf16 in MFMA B-operand fragment order.
// u-chunk = 64, c in 0..3.
// B1 region: fid = ((c*6+kt)*16+ct)*64+lane              (24576 frags)
//   elem e: kc = kt*32+(lane>>4)*8+e (0..191), seg=kc>>6, u=c*64+(kc&63),
//   w = ct*16+(lane&15); seg0->W2, seg1->W3 (A1/sqrt3), seg2->W5 (A1/sqrt6)
// B0 region: fid = 24576 + ((c*4+kt)*16+ct)*64+lane      (16384 frags)
//   kc in 0..127, seg=kc>>6; seg0->W1 (A0), seg1->W4 (A0/sqrt3)
// ---------------------------------------------------------------------------
__global__ __launch_bounds__(256) void prep_weights(
    const float* __restrict__ wgt, unsigned short* __restrict__ Bw)
{
  int fid = blockIdx.x * 256 + threadIdx.x;
  union { unsigned short h[8]; int4 v; } pk;
  if (fid < 24576) {
    int lane = fid & 63;
    int ct = (fid >> 6) & 15;
    int q = fid >> 10;            // 0..23 = c*6 + kt
    int kt = q % 6, c = q / 6;
    int w = ct * 16 + (lane & 15);
    int kh = (lane >> 4) * 8;
#pragma unroll
    for (int e = 0; e < 8; ++e) {
      int kc = kt * 32 + kh + e;       // 0..191
      int seg = kc >> 6;
      int u = c * 64 + (kc & 63);
      float s  = (seg == 2) ? 0.025515518153991442f : 0.03608439182435161f;
      int off  = (seg == 0) ? 65536 : (seg == 1 ? 131072 : 262144);
      pk.h[e] = f2bf(wgt[off + u * 256 + w] * s);
    }
    ((int4*)Bw)[fid] = pk.v;
  } else if (fid < 40960) {
    int f2 = fid - 24576;
    int lane = f2 & 63;
    int ct = (f2 >> 6) & 15;
    int q = f2 >> 10;             // 0..15 = c*4 + kt
    int kt = q & 3, c = q >> 2;
    int w = ct * 16 + (lane & 15);
    int kh = (lane >> 4) * 8;
#pragma unroll
    for (int e = 0; e < 8; ++e) {
      int kc = kt * 32 + kh + e;       // 0..127
      int seg = kc >> 6;
      int u = c * 64 + (kc & 63);
      float s  = (seg == 0) ? 0.04419417382415922f : 0.025515518153991442f;
      int off  = (seg == 0) ? 0 : 196608;
      pk.h[e] = f2bf(wgt[off + u * 256 + w] * s);
    }
    ((int4*)Bw)[fid] = pk.v;
  }
}

// LDS map (int4 slots): T1 rt*384 + kt*64 + perm  (rt 0..5, kt 0..5)
//                       T0 2304 + rt*256 + kt*64 + perm (rt 0..1, kt 0..3)
#define T0BASE 2304

struct X1Regs {
  float4 s[2];   // s1[u .. u+8)
  float4 v[6];   // v1[(u..u+8), 0..3) interleaved: f[3e+k]
};

static __device__ __forceinline__ void load_x1(
    X1Regs& r, const float* __restrict__ x1, int zrow, int ub, int rr)
{
  const float* base = x1 + (size_t)zrow * 1024;
  const float4* ps = (const float4*)(base + ub + rr * 8);
  r.s[0] = ps[0]; r.s[1] = ps[1];
  const float4* pv = (const float4*)(base + 256 + 3 * ub + rr * 24);
#pragma unroll
  for (int i = 0; i < 6; ++i) r.v[i] = pv[i];
}

// thread (zl 0..31, rr 0..7) owns u-run [rr*8, rr*8+8) of the 64-u chunk.
// kt = sg*2 + (rr>>2); lane-half lh = rr&3; elem e -> kc = kt*32 + lh*8 + e.
static __device__ __forceinline__ void build_frags(
    const X1Regs& r, int zl, int rr, float s2, const float* v2, int4* ldsT)
{
  union { float4 q[2]; float f[8]; } s1u;
  s1u.q[0] = r.s[0]; s1u.q[1] = r.s[1];
  union { float4 q[6]; float f[24]; } v1u;
#pragma unroll
  for (int i = 0; i < 6; ++i) v1u.q[i] = r.v[i];
  const int lh = rr & 3;
  const int kq = rr >> 2;

  // ---- T1: seg 0..2 x comp k 0..2 ; row = 3*zl + k (0..95)
#pragma unroll
  for (int sg = 0; sg < 3; ++sg) {
#pragma unroll
    for (int k = 0; k < 3; ++k) {
      int row = 3 * zl + k;
      int kt  = sg * 2 + kq;
      int fl  = (((lh << 4) | (row & 15)) ^ (kt & 7)) ^ lh;
      int addr = (row >> 4) * 384 + kt * 64 + fl;
      float t[8];
      if (sg == 0) {                     // s1 * v2[k]      (-> W2)
#pragma unroll
        for (int e = 0; e < 8; ++e) t[e] = s1u.f[e] * v2[k];
      } else if (sg == 1) {              // v1[.,k] * s2    (-> W3)
#pragma unroll
        for (int e = 0; e < 8; ++e) t[e] = v1u.f[3 * e + k] * s2;
      } else {                           // (v1 x v2)[k]    (-> W5)
        int k1 = k + 1; if (k1 > 2) k1 -= 3;
        int k2 = k + 2; if (k2 > 2) k2 -= 3;
#pragma unroll
        for (int e = 0; e < 8; ++e)
          t[e] = v1u.f[3 * e + k1] * v2[k2] - v1u.f[3 * e + k2] * v2[k1];
      }
      union { unsigned short h[8]; int4 v; } pk;
#pragma unroll
      for (int e = 0; e < 8; ++e) pk.h[e] = f2bf(t[e]);
      ldsT[addr] = pk.v;
    }
  }
  // ---- T0: seg 0..1 ; row = zl (0..31)
#pragma unroll
  for (int sg = 0; sg < 2; ++sg) {
    int kt = sg * 2 + kq;
    int fl = (((lh << 4) | (zl & 15)) ^ (kt & 7)) ^ lh;
    int addr = T0BASE + (zl >> 4) * 256 + kt * 64 + fl;
    float t[8];
    if (sg == 0) {                       // s1 * s2         (-> W1)
#pragma unroll
      for (int e = 0; e < 8; ++e) t[e] = s1u.f[e] * s2;
    } else {                             // v1 . v2         (-> W4)
#pragma unroll
      for (int e = 0; e < 8; ++e)
        t[e] = v1u.f[3 * e] * v2[0] + v1u.f[3 * e + 1] * v2[1]
             + v1u.f[3 * e + 2] * v2[2];
    }
    union { unsigned short h[8]; int4 v; } pk;
#pragma unroll
    for (int e = 0; e < 8; ++e) pk.h[e] = f2bf(t[e]);
    ldsT[addr] = pk.v;
  }
}

static __device__ __forceinline__ void gemm_chunk(
    int c, int lane, int wid, const int4* ldsT,
    const int4* __restrict__ B1v, const int4* __restrict__ B0v,
    f32x4 acc1[6][4], f32x4 acc0[2][4])
{
  int4 b[4];
  {
    const int4* bp = B1v + ((size_t)(c * 6) * 16 + wid * 4) * 64 + lane;
    b[0] = bp[0]; b[1] = bp[64]; b[2] = bp[128]; b[3] = bp[192];
  }
  // ---- out1: 6 kt steps, 24 MFMA each; B prefetch chains into out0
#pragma unroll 1
  for (int kt = 0; kt < 6; ++kt) {
    int4 a[6];
    int fl = (lane ^ (kt & 7)) ^ (lane >> 4);
#pragma unroll
    for (int rt = 0; rt < 6; ++rt) a[rt] = ldsT[rt * 384 + kt * 64 + fl];
    const int4* np = (kt < 5)
        ? B1v + ((size_t)(c * 6 + kt + 1) * 16 + wid * 4) * 64 + lane
        : B0v + ((size_t)(c * 4) * 16 + wid * 4) * 64 + lane;
    int4 bn[4];
    bn[0] = np[0]; bn[1] = np[64]; bn[2] = np[128]; bn[3] = np[192];
#pragma unroll
    for (int rt = 0; rt < 6; ++rt) {
      bf16x8 av = asbf(a[rt]);
#pragma unroll
      for (int ct = 0; ct < 4; ++ct)
        acc1[rt][ct] = __builtin_amdgcn_mfma_f32_16x16x32_bf16(
            av, asbf(b[ct]), acc1[rt][ct], 0, 0, 0);
    }
    b[0] = bn[0]; b[1] = bn[1]; b[2] = bn[2]; b[3] = bn[3];
  }
  // ---- out0: 4 kt steps, 8 MFMA each (b already holds B0 kt=0)
#pragma unroll 1
  for (int kt = 0; kt < 4; ++kt) {
    int4 a[2];
    int fl = (lane ^ (kt & 7)) ^ (lane >> 4);
    a[0] = ldsT[T0BASE + kt * 64 + fl];
    a[1] = ldsT[T0BASE + 256 + kt * 64 + fl];
    int4 bn[4];
    if (kt < 3) {
      const int4* np = B0v + ((size_t)(c * 4 + kt + 1) * 16 + wid * 4) * 64 + lane;
      bn[0] = np[0]; bn[1] = np[64]; bn[2] = np[128]; bn[3] = np[192];
    } else {
      bn[0] = b[0]; bn[1] = b[1]; bn[2] = b[2]; bn[3] = b[3];
    }
#pragma unroll
    for (int rt = 0; rt < 2; ++rt) {
      bf16x8 av = asbf(a[rt]);
#pragma unroll
      for (int ct = 0; ct < 4; ++ct)
        acc0[rt][ct] = __builtin_amdgcn_mfma_f32_16x16x32_bf16(
            av, asbf(b[ct]), acc0[rt][ct], 0, 0, 0);
    }
    b[0] = bn[0]; b[1] = bn[1]; b[2] = bn[2]; b[3] = bn[3];
  }
}

// ---------------------------------------------------------------------------
// Main kernel: 32 z-rows per block, 256 threads (4 waves), full 256 out-cols.
// LDS = (2304 + 512) int4 = 45 KB. 4 u-chunks of 64; x1 chunk c+1 loads
// issued before gemm(c) (latency hidden under GEMM's MFMA + B loads).
// ---------------------------------------------------------------------------
__global__ __launch_bounds__(256, 2) void tp_main(
    const float* __restrict__ x1, const float* __restrict__ x2,
    const int4* __restrict__ B1v, const int4* __restrict__ B0v,
    float* __restrict__ out)
{
  __shared__ int4 ldsT[2816];           // 45056 bytes
  const int tid  = threadIdx.x;
  const int lane = tid & 63;
  const int wid  = tid >> 6;            // wave = output col-quarter
  const int z0   = blockIdx.x * 32;
  const int zl   = tid >> 3;            // T-build row ownership (0..31)
  const int rr   = tid & 7;             // T-build u-run ownership (0..7)

  f32x4 acc1[6][4];
  f32x4 acc0[2][4];
#pragma unroll
  for (int i = 0; i < 6; ++i)
#pragma unroll
    for (int j = 0; j < 4; ++j) acc1[i][j] = (f32x4){0.f, 0.f, 0.f, 0.f};
#pragma unroll
  for (int i = 0; i < 2; ++i)
#pragma unroll
    for (int j = 0; j < 4; ++j) acc0[i][j] = (f32x4){0.f, 0.f, 0.f, 0.f};

  // x2 row values (broadcast per 8 threads)
  float4 x2v = ((const float4*)x2)[z0 + zl];
  const float s2 = x2v.x;
  float v2[3] = {x2v.y, x2v.z, x2v.w};

  X1Regs r;
  load_x1(r, x1, z0 + zl, 0, rr);
  build_frags(r, zl, rr, s2, v2, ldsT);
  __syncthreads();

  load_x1(r, x1, z0 + zl, 64, rr);      // chunk 1 in flight under gemm(0)
  gemm_chunk(0, lane, wid, ldsT, B1v, B0v, acc1, acc0);
  __syncthreads();
  build_frags(r, zl, rr, s2, v2, ldsT);
  __syncthreads();

  load_x1(r, x1, z0 + zl, 128, rr);
  gemm_chunk(1, lane, wid, ldsT, B1v, B0v, acc1, acc0);
  __syncthreads();
  build_frags(r, zl, rr, s2, v2, ldsT);
  __syncthreads();

  load_x1(r, x1, z0 + zl, 192, rr);
  gemm_chunk(2, lane, wid, ldsT, B1v, B0v, acc1, acc0);
  __syncthreads();
  build_frags(r, zl, rr, s2, v2, ldsT);
  __syncthreads();

  gemm_chunk(3, lane, wid, ldsT, B1v, B0v, acc1, acc0);

  // ---- epilogue: accumulators are the final outputs
  const int col = lane & 15;
  const int rb  = (lane >> 4) * 4;       // C/D: col=lane&15, row=(lane>>4)*4+reg
#pragma unroll
  for (int rt = 0; rt < 2; ++rt) {
#pragma unroll
    for (int ct = 0; ct < 4; ++ct) {
      int w = (wid * 4 + ct) * 16 + col;
#pragma unroll
      for (int rg = 0; rg < 4; ++rg) {
        int row = rt * 16 + rb + rg;     // zl 0..31
        out[(size_t)(z0 + row) * 1024 + w] = acc0[rt][ct][rg];
      }
    }
  }
#pragma unroll
  for (int rt = 0; rt < 6; ++rt) {
#pragma unroll
    for (int ct = 0; ct < 4; ++ct) {
      int w = (wid * 4 + ct) * 16 + col;
#pragma unroll
      for (int rg = 0; rg < 4; ++rg) {
        int row = rt * 16 + rb + rg;     // 0..95 ; row = 3*zl + k
        int zz = row / 3;
        int k  = row - zz * 3;
        out[(size_t)(z0 + zz) * 1024 + 256 + w * 3 + k] = acc1[rt][ct][rg];
      }
    }
  }
}

// ---------------------------------------------------------------------------
extern "C" void kernel_launch(void* const* d_in, const int* in_sizes, int n_in,
                              void* d_out, int out_size, void* d_ws, size_t ws_size,
                              hipStream_t stream) {
  const float* x1  = (const float*)d_in[0];   // (n, 1024) f32
  const float* x2  = (const float*)d_in[1];   // (n, 4)    f32
  const float* wgt = (const float*)d_in[2];   // (327680,) f32
  float* out = (float*)d_out;                 // (n, 1024) f32

  // ws: B1 fragments [0, 393216) + B0 fragments [393216, 655360)  (bf16)
  unsigned short* Bw = (unsigned short*)d_ws;
  const int4* B1v = (const int4*)Bw;
  const int4* B0v = B1v + 24576;

  int n = in_sizes[0] / 1024;                 // 20000 (divisible by 32)

  prep_weights<<<160, 256, 0, stream>>>(wgt, Bw);
  tp_main<<<n / 32, 256, 0, stream>>>(x1, x2, B1v, B0v, out);
}

// Round 4
// 80.730 us; speedup vs baseline: 1.0270x; 1.0270x over previous
//
#include <hip/hip_runtime.h>

// Simple_TensorProduct (e3nn uvw TP, MUL=256, l<=1, v=1) as two fused bf16 GEMMs.
//   out0[z,w]      = sum_k T0[z,k]    * B0[k,w]   (K=512)
//   out1[(z,c),w]  = sum_k T1[(z,c),k]* B1[k,w]   (K=768, M=3N)
// T = x1 with x2 folded in (built per z-tile, bf16, LDS, A-fragment order).
// B = weights, prescaled by path alphas, bf16, B-fragment order in d_ws.
//
// R4: TLP-first. z=16 (1250 blocks = 4.9 blocks/CU of work), u-chunk=64
// (4 chunks), LDS 22.5 KB (cap 7 blocks/CU), __launch_bounds__(256,4) to
// force VGPR<=128 -> 4 blocks/CU resident. No register double-buffering of
// A/B (R2/R3 showed the compiler defeats it; TLP hides L2 latency); only the
// x1 next-chunk prefetch is kept (HBM latency too long for TLP alone).
// Build: thread (zl 0..15, rr 0..15) owns a 4-u run -> ds_write_b64 halves.

typedef short bf16x8 __attribute__((ext_vector_type(8)));
typedef float f32x4 __attribute__((ext_vector_type(4)));

static __device__ __forceinline__ unsigned short f2bf(float f) {
  unsigned int u = __builtin_bit_cast(unsigned int, f);
  u += 0x7FFFu + ((u >> 16) & 1u);   // RNE
  return (unsigned short)(u >> 16);
}

static __device__ __forceinline__ bf16x8 asbf(int4 v) {
  return __builtin_bit_cast(bf16x8, v);
}

// ---------------------------------------------------------------------------
// Weight prep (identical layout to R3): u-chunk = 64, c in 0..3.
// B1 region: fid = ((c*6+kt)*16+ct)*64+lane              (24576 frags)
//   elem e: kc = kt*32+(lane>>4)*8+e (0..191), seg=kc>>6, u=c*64+(kc&63),
//   w = ct*16+(lane&15); seg0->W2, seg1->W3 (A1/sqrt3), seg2->W5 (A1/sqrt6)
// B0 region: fid = 24576 + ((c*4+kt)*16+ct)*64+lane      (16384 frags)
//   kc in 0..127, seg=kc>>6; seg0->W1 (A0), seg1->W4 (A0/sqrt3)
// ---------------------------------------------------------------------------
__global__ __launch_bounds__(256) void prep_weights(
    const float* __restrict__ wgt, unsigned short* __restrict__ Bw)
{
  int fid = blockIdx.x * 256 + threadIdx.x;
  union { unsigned short h[8]; int4 v; } pk;
  if (fid < 24576) {
    int lane = fid & 63;
    int ct = (fid >> 6) & 15;
    int q = fid >> 10;            // 0..23 = c*6 + kt
    int kt = q % 6, c = q / 6;
    int w = ct * 16 + (lane & 15);
    int kh = (lane >> 4) * 8;
#pragma unroll
    for (int e = 0; e < 8; ++e) {
      int kc = kt * 32 + kh + e;       // 0..191
      int seg = kc >> 6;
      int u = c * 64 + (kc & 63);
      float s  = (seg == 2) ? 0.025515518153991442f : 0.03608439182435161f;
      int off  = (seg == 0) ? 65536 : (seg == 1 ? 131072 : 262144);
      pk.h[e] = f2bf(wgt[off + u * 256 + w] * s);
    }
    ((int4*)Bw)[fid] = pk.v;
  } else if (fid < 40960) {
    int f2 = fid - 24576;
    int lane = f2 & 63;
    int ct = (f2 >> 6) & 15;
    int q = f2 >> 10;             // 0..15 = c*4 + kt
    int kt = q & 3, c = q >> 2;
    int w = ct * 16 + (lane & 15);
    int kh = (lane >> 4) * 8;
#pragma unroll
    for (int e = 0; e < 8; ++e) {
      int kc = kt * 32 + kh + e;       // 0..127
      int seg = kc >> 6;
      int u = c * 64 + (kc & 63);
      float s  = (seg == 0) ? 0.04419417382415922f : 0.025515518153991442f;
      int off  = (seg == 0) ? 0 : 196608;
      pk.h[e] = f2bf(wgt[off + u * 256 + w] * s);
    }
    ((int4*)Bw)[fid] = pk.v;
  }
}

// LDS map (int4 slots): T1 rt*384 + kt*64 + perm  (rt 0..2, kt 0..5)
//                       T0 1152 + kt*64 + perm    (kt 0..3)
#define T0BASE 1152

struct X1Regs {
  float4 s;      // s1[u .. u+4)
  float4 v[3];   // v1[(u..u+4), 0..3) interleaved: f[3e+k]
};

static __device__ __forceinline__ void load_x1(
    X1Regs& r, const float* __restrict__ x1, int zrow, int ub, int rr)
{
  const float* base = x1 + (size_t)zrow * 1024;
  r.s = *(const float4*)(base + ub + rr * 4);
  const float4* pv = (const float4*)(base + 256 + 3 * ub + rr * 12);
#pragma unroll
  for (int i = 0; i < 3; ++i) r.v[i] = pv[i];
}

// thread (zl 0..15, rr 0..15) owns u-run [rr*4, rr*4+4) of the 64-u chunk.
// kc = sg*64 + rr*4 + e -> kt = sg*2 + (rr>>3), lane-half lh = (rr>>1)&3,
// within-fragment half = rr&1 (8 bytes).
static __device__ __forceinline__ void build_frags(
    const X1Regs& r, int zl, int rr, float s2, const float* v2, int4* ldsT)
{
  union { float4 q; float f[4]; } s1u;
  s1u.q = r.s;
  union { float4 q[3]; float f[12]; } v1u;
#pragma unroll
  for (int i = 0; i < 3; ++i) v1u.q[i] = r.v[i];
  const int lh   = (rr >> 1) & 3;
  const int kq   = rr >> 3;
  const int half = rr & 1;
  int2* lds2 = (int2*)ldsT;

  // ---- T1: seg 0..2 x comp k 0..2 ; row = 3*zl + k (0..47)
#pragma unroll
  for (int sg = 0; sg < 3; ++sg) {
#pragma unroll
    for (int k = 0; k < 3; ++k) {
      int row = 3 * zl + k;
      int kt  = sg * 2 + kq;
      int fl  = (((lh << 4) | (row & 15)) ^ (kt & 7)) ^ lh;
      int slot = (row >> 4) * 384 + kt * 64 + fl;
      float t[4];
      if (sg == 0) {                     // s1 * v2[k]      (-> W2)
#pragma unroll
        for (int e = 0; e < 4; ++e) t[e] = s1u.f[e] * v2[k];
      } else if (sg == 1) {              // v1[.,k] * s2    (-> W3)
#pragma unroll
        for (int e = 0; e < 4; ++e) t[e] = v1u.f[3 * e + k] * s2;
      } else {                           // (v1 x v2)[k]    (-> W5)
        int k1 = k + 1; if (k1 > 2) k1 -= 3;
        int k2 = k + 2; if (k2 > 2) k2 -= 3;
#pragma unroll
        for (int e = 0; e < 4; ++e)
          t[e] = v1u.f[3 * e + k1] * v2[k2] - v1u.f[3 * e + k2] * v2[k1];
      }
      union { unsigned short h[4]; int2 v; } pk;
#pragma unroll
      for (int e = 0; e < 4; ++e) pk.h[e] = f2bf(t[e]);
      lds2[slot * 2 + half] = pk.v;
    }
  }
  // ---- T0: seg 0..1 ; row = zl (0..15)
#pragma unroll
  for (int sg = 0; sg < 2; ++sg) {
    int kt = sg * 2 + kq;
    int fl = (((lh << 4) | zl) ^ (kt & 7)) ^ lh;
    int slot = T0BASE + kt * 64 + fl;
    float t[4];
    if (sg == 0) {                       // s1 * s2         (-> W1)
#pragma unroll
      for (int e = 0; e < 4; ++e) t[e] = s1u.f[e] * s2;
    } else {                             // v1 . v2         (-> W4)
#pragma unroll
      for (int e = 0; e < 4; ++e)
        t[e] = v1u.f[3 * e] * v2[0] + v1u.f[3 * e + 1] * v2[1]
             + v1u.f[3 * e + 2] * v2[2];
    }
    union { unsigned short h[4]; int2 v; } pk;
#pragma unroll
    for (int e = 0; e < 4; ++e) pk.h[e] = f2bf(t[e]);
    lds2[slot * 2 + half] = pk.v;
  }
}

static __device__ __forceinline__ void gemm_chunk(
    int c, int lane, int wid, const int4* ldsT,
    const int4* __restrict__ B1v, const int4* __restrict__ B0v,
    f32x4 acc1[3][4], f32x4 acc0[4])
{
  // ---- out1: 6 kt steps, 12 MFMA each. Loads at top; TLP hides latency.
#pragma unroll 1
  for (int kt = 0; kt < 6; ++kt) {
    const int4* bp = B1v + ((c * 6 + kt) * 16 + wid * 4) * 64 + lane;
    int4 b0 = bp[0], b1 = bp[64], b2 = bp[128], b3 = bp[192];
    int fl = (lane ^ (kt & 7)) ^ (lane >> 4);
    int4 a0 = ldsT[kt * 64 + fl];
    int4 a1 = ldsT[384 + kt * 64 + fl];
    int4 a2 = ldsT[768 + kt * 64 + fl];
    int4 a[3] = {a0, a1, a2};
    int4 b[4] = {b0, b1, b2, b3};
#pragma unroll
    for (int rt = 0; rt < 3; ++rt) {
      bf16x8 av = asbf(a[rt]);
#pragma unroll
      for (int ct = 0; ct < 4; ++ct)
        acc1[rt][ct] = __builtin_amdgcn_mfma_f32_16x16x32_bf16(
            av, asbf(b[ct]), acc1[rt][ct], 0, 0, 0);
    }
  }
  // ---- out0: 4 kt steps, 4 MFMA each
#pragma unroll 1
  for (int kt = 0; kt < 4; ++kt) {
    const int4* bp = B0v + ((c * 4 + kt) * 16 + wid * 4) * 64 + lane;
    int4 b0 = bp[0], b1 = bp[64], b2 = bp[128], b3 = bp[192];
    int fl = (lane ^ (kt & 7)) ^ (lane >> 4);
    int4 a0 = ldsT[T0BASE + kt * 64 + fl];
    int4 b[4] = {b0, b1, b2, b3};
    bf16x8 av = asbf(a0);
#pragma unroll
    for (int ct = 0; ct < 4; ++ct)
      acc0[ct] = __builtin_amdgcn_mfma_f32_16x16x32_bf16(
          av, asbf(b[ct]), acc0[ct], 0, 0, 0);
  }
}

// ---------------------------------------------------------------------------
// Main kernel: 16 z-rows per block, 256 threads (4 waves), full 256 out-cols.
// LDS = 1408 int4 = 22528 B. 4 u-chunks of 64; x1 chunk c+1 loads issued
// before gemm(c).
// ---------------------------------------------------------------------------
__global__ __launch_bounds__(256, 4) void tp_main(
    const float* __restrict__ x1, const float* __restrict__ x2,
    const int4* __restrict__ B1v, const int4* __restrict__ B0v,
    float* __restrict__ out)
{
  __shared__ int4 ldsT[1408];           // 22528 bytes
  const int tid  = threadIdx.x;
  const int lane = tid & 63;
  const int wid  = tid >> 6;            // wave = output col-quarter
  const int z0   = blockIdx.x * 16;
  const int zl   = tid >> 4;            // T-build row ownership (0..15)
  const int rr   = tid & 15;            // T-build u-run ownership (0..15)

  f32x4 acc1[3][4];
  f32x4 acc0[4];
#pragma unroll
  for (int i = 0; i < 3; ++i)
#pragma unroll
    for (int j = 0; j < 4; ++j) acc1[i][j] = (f32x4){0.f, 0.f, 0.f, 0.f};
#pragma unroll
  for (int j = 0; j < 4; ++j) acc0[j] = (f32x4){0.f, 0.f, 0.f, 0.f};

  // x2 row values (broadcast per 16 threads)
  float4 x2v = ((const float4*)x2)[z0 + zl];
  const float s2 = x2v.x;
  float v2[3] = {x2v.y, x2v.z, x2v.w};

  X1Regs r;
  load_x1(r, x1, z0 + zl, 0, rr);
  build_frags(r, zl, rr, s2, v2, ldsT);
  __syncthreads();

  load_x1(r, x1, z0 + zl, 64, rr);      // chunk 1 in flight under gemm(0)
  gemm_chunk(0, lane, wid, ldsT, B1v, B0v, acc1, acc0);
  __syncthreads();
  build_frags(r, zl, rr, s2, v2, ldsT);
  __syncthreads();

  load_x1(r, x1, z0 + zl, 128, rr);
  gemm_chunk(1, lane, wid, ldsT, B1v, B0v, acc1, acc0);
  __syncthreads();
  build_frags(r, zl, rr, s2, v2, ldsT);
  __syncthreads();

  load_x1(r, x1, z0 + zl, 192, rr);
  gemm_chunk(2, lane, wid, ldsT, B1v, B0v, acc1, acc0);
  __syncthreads();
  build_frags(r, zl, rr, s2, v2, ldsT);
  __syncthreads();

  gemm_chunk(3, lane, wid, ldsT, B1v, B0v, acc1, acc0);

  // ---- epilogue: accumulators are the final outputs
  const int col = lane & 15;
  const int rb  = (lane >> 4) * 4;       // C/D: col=lane&15, row=(lane>>4)*4+reg
#pragma unroll
  for (int ct = 0; ct < 4; ++ct) {
    int w = (wid * 4 + ct) * 16 + col;
#pragma unroll
    for (int rg = 0; rg < 4; ++rg) {
      int row = rb + rg;                 // zl 0..15
      out[(size_t)(z0 + row) * 1024 + w] = acc0[ct][rg];
    }
  }
#pragma unroll
  for (int rt = 0; rt < 3; ++rt) {
#pragma unroll
    for (int ct = 0; ct < 4; ++ct) {
      int w = (wid * 4 + ct) * 16 + col;
#pragma unroll
      for (int rg = 0; rg < 4; ++rg) {
        int row = rt * 16 + rb + rg;     // 0..47 ; row = 3*zl + k
        int zz = row / 3;
        int k  = row - zz * 3;
        out[(size_t)(z0 + zz) * 1024 + 256 + w * 3 + k] = acc1[rt][ct][rg];
      }
    }
  }
}

// ---------------------------------------------------------------------------
extern "C" void kernel_launch(void* const* d_in, const int* in_sizes, int n_in,
                              void* d_out, int out_size, void* d_ws, size_t ws_size,
                              hipStream_t stream) {
  const float* x1  = (const float*)d_in[0];   // (n, 1024) f32
  const float* x2  = (const float*)d_in[1];   // (n, 4)    f32
  const float* wgt = (const float*)d_in[2];   // (327680,) f32
  float* out = (float*)d_out;                 // (n, 1024) f32

  // ws: B1 fragments [0, 393216) + B0 fragments [393216, 655360)  (bf16)
  unsigned short* Bw = (unsigned short*)d_ws;
  const int4* B1v = (const int4*)Bw;
  const int4* B0v = B1v + 24576;

  int n = in_sizes[0] / 1024;                 // 20000 (divisible by 16)

  prep_weights<<<160, 256, 0, stream>>>(wgt, Bw);
  tp_main<<<n / 16, 256, 0, stream>>>(x1, x2, B1v, B0v, out);
}